// Round 10
// baseline (890.797 us; speedup 1.0000x reference)
//
#include <hip/hip_runtime.h>
#include <stdint.h>

// MultiHeadAttention w/ RoPE, causal. B=2, T=2048, C=1024, H=16, Dh=64.
// Round 10: ROOT CAUSE FOUND — d_out is FP32 (reference output dtype), I had
// been writing bf16. R5 MFMA pipeline restored (values certified by the
// R5==R6==R7 absmax fingerprint + R9 S1 probe); final GEMM now stores fp32.

typedef float  f32x4  __attribute__((ext_vector_type(4)));
typedef __bf16 bf16x8 __attribute__((ext_vector_type(8)));

static __device__ __forceinline__ f32x4 zero4() {
  f32x4 z = {0.f, 0.f, 0.f, 0.f};
  return z;
}

// load 8 contiguous fp32 and round to bf16x8
static __device__ __forceinline__ bf16x8 cvt8(const float* __restrict__ p) {
  f32x4 u = *(const f32x4*)p;
  f32x4 v = *(const f32x4*)(p + 4);
  bf16x8 o;
#pragma unroll
  for (int j = 0; j < 4; ++j) o[j] = (__bf16)u[j];
#pragma unroll
  for (int j = 0; j < 4; ++j) o[4 + j] = (__bf16)v[j];
  return o;
}

// ---------------------------------------------------------------------------
// NT GEMM: C[m][n] = sum_k A[m][k] * Bt[n][k];  M=4096, N=1024, K=1024.
// 128x128 tile, BK=32, 4 waves (2x2 of 64x64), mfma_f32_16x16x32_bf16.
// plain=0 -> z selects {Q,K,V}: RoPE (z<2) + head-layout scatter (bf16).
// plain=1 -> row-major FP32 store to Of.
// ---------------------------------------------------------------------------
#define ASTR 40  // 128x32 LDS tile, row stride 40 elem (80 B, 16B-aligned)

__global__ __launch_bounds__(256) void gemm_nt(
    const void* __restrict__ Av,
    const void* __restrict__ W0, const void* __restrict__ W1,
    const void* __restrict__ W2,
    __bf16* __restrict__ O0, __bf16* __restrict__ O1, __bf16* __restrict__ O2,
    float* __restrict__ Of,
    int plain, int a_f32, int b_f32)
{
  __shared__ __bf16 As[128 * ASTR];
  __shared__ __bf16 Bs[128 * ASTR];

  const int tid  = threadIdx.x;
  const int lane = tid & 63;
  const int wid  = tid >> 6;
  const int quad = lane >> 4;
  const int l16  = lane & 15;
  const int wm   = (wid >> 1) * 64;
  const int wn   = (wid & 1) * 64;
  const int n0   = blockIdx.x * 128;
  const int m0   = blockIdx.y * 128;
  const int z    = blockIdx.z;
  const void* Btv = (z == 0) ? W0 : (z == 1) ? W1 : W2;

  const int r0 = tid >> 2, c0 = tid & 3;
  const int r1 = (tid + 256) >> 2;

  f32x4 acc[4][4];
  for (int i = 0; i < 4; ++i)
    for (int j = 0; j < 4; ++j) acc[i][j] = zero4();

  for (int k0 = 0; k0 < 1024; k0 += 32) {
    bf16x8 a0, a1, b0, b1;
    if (a_f32) {
      const float* Af = (const float*)Av;
      a0 = cvt8(&Af[(size_t)(m0 + r0) * 1024 + k0 + c0 * 8]);
      a1 = cvt8(&Af[(size_t)(m0 + r1) * 1024 + k0 + c0 * 8]);
    } else {
      const __bf16* Ab = (const __bf16*)Av;
      a0 = *(const bf16x8*)&Ab[(size_t)(m0 + r0) * 1024 + k0 + c0 * 8];
      a1 = *(const bf16x8*)&Ab[(size_t)(m0 + r1) * 1024 + k0 + c0 * 8];
    }
    if (b_f32) {
      const float* Bf = (const float*)Btv;
      b0 = cvt8(&Bf[(size_t)(n0 + r0) * 1024 + k0 + c0 * 8]);
      b1 = cvt8(&Bf[(size_t)(n0 + r1) * 1024 + k0 + c0 * 8]);
    } else {
      const __bf16* Bb = (const __bf16*)Btv;
      b0 = *(const bf16x8*)&Bb[(size_t)(n0 + r0) * 1024 + k0 + c0 * 8];
      b1 = *(const bf16x8*)&Bb[(size_t)(n0 + r1) * 1024 + k0 + c0 * 8];
    }
    __syncthreads();
    *(bf16x8*)&As[r0 * ASTR + c0 * 8] = a0;
    *(bf16x8*)&As[r1 * ASTR + c0 * 8] = a1;
    *(bf16x8*)&Bs[r0 * ASTR + c0 * 8] = b0;
    *(bf16x8*)&Bs[r1 * ASTR + c0 * 8] = b1;
    __syncthreads();

    bf16x8 af[4], bfr[4];
    for (int i = 0; i < 4; ++i)
      af[i] = *(const bf16x8*)&As[(wm + i * 16 + l16) * ASTR + quad * 8];
    for (int i = 0; i < 4; ++i)
      bfr[i] = *(const bf16x8*)&Bs[(wn + i * 16 + l16) * ASTR + quad * 8];
    for (int mt = 0; mt < 4; ++mt)
      for (int nt = 0; nt < 4; ++nt)
        acc[mt][nt] = __builtin_amdgcn_mfma_f32_16x16x32_bf16(
            af[mt], bfr[nt], acc[mt][nt], 0, 0, 0);
  }

  // ---- epilogue ----  D layout: row = 4*quad + reg, col = l16 per subtile.
  if (plain) {
    for (int mt = 0; mt < 4; ++mt)
      for (int r = 0; r < 4; ++r) {
        int gm = m0 + wm + mt * 16 + 4 * quad + r;
        for (int nt = 0; nt < 4; ++nt) {
          int gn = n0 + wn + nt * 16 + l16;
          Of[(size_t)gm * 1024 + gn] = acc[mt][nt][r];   // FP32 output
        }
      }
    return;
  }

  const int h = (n0 + wn) >> 6;  // each wave covers exactly one head
  if (z < 2) {
    // RoPE: d in [0,32) pairs with d+32 -> acc[mt][nt] with acc[mt][nt+2].
    const float c0f = -13.287712379549449f / 32.0f;  // -log2(10000)/32
    const float f0 = exp2f((float)l16 * c0f);
    const float f1 = exp2f((float)(16 + l16) * c0f);
    for (int mt = 0; mt < 4; ++mt)
      for (int r = 0; r < 4; ++r) {
        int gm = m0 + wm + mt * 16 + 4 * quad + r;
        float t = (float)(gm & 2047);
        for (int nt = 0; nt < 2; ++nt) {
          float ang = t * (nt ? f1 : f0);
          float cv = cosf(ang), sv = sinf(ang);
          float lo = acc[mt][nt][r], hi = acc[mt][nt + 2][r];
          acc[mt][nt][r]     = lo * cv - hi * sv;
          acc[mt][nt + 2][r] = hi * cv + lo * sv;
        }
      }
    __bf16* dst = (z == 0) ? O0 : O1;
    for (int mt = 0; mt < 4; ++mt)
      for (int r = 0; r < 4; ++r) {
        int gm = m0 + wm + mt * 16 + 4 * quad + r;
        int b = gm >> 11, t = gm & 2047;
        size_t base = ((size_t)(b * 16 + h) * 2048 + t) * 64;
        for (int nt = 0; nt < 4; ++nt)
          dst[base + nt * 16 + l16] = (__bf16)acc[mt][nt][r];
      }
  } else {
    // V stored transposed: Vt[b*16+h][d][t]
    for (int mt = 0; mt < 4; ++mt)
      for (int r = 0; r < 4; ++r) {
        int gm = m0 + wm + mt * 16 + 4 * quad + r;
        int b = gm >> 11, t = gm & 2047;
        size_t hb = (size_t)(b * 16 + h) * 64;
        for (int nt = 0; nt < 4; ++nt) {
          int d = nt * 16 + l16;
          O2[((hb + d) << 11) + t] = (__bf16)acc[mt][nt][r];
        }
      }
  }
}

// ---------------------------------------------------------------------------
// Flash attention (causal). One block = 64 q-rows of one (b,h); 4 waves,
// wave w owns q-rows [w*16, w*16+16). Br=Bc=64, Dh=64.
// Q[bh][t][d], K[bh][t][d], V transposed Vt[bh][d][t]. Padded LDS (stride 72).
// ---------------------------------------------------------------------------
__global__ __launch_bounds__(256) void attn_fwd(
    const __bf16* __restrict__ Qh, const __bf16* __restrict__ Kh,
    const __bf16* __restrict__ Vt, __bf16* __restrict__ AO)
{
  __shared__ __bf16 Ks[64 * 72];   // [kpos][d]
  __shared__ __bf16 Vs[64 * 72];   // [d][kpos]
  __shared__ __bf16 Ps[64 * 72];   // [q][kpos]

  const int tid  = threadIdx.x;
  const int lane = tid & 63, wid = tid >> 6;
  const int quad = lane >> 4, l16 = lane & 15;
  const int bh = blockIdx.y;
  const int q0 = blockIdx.x * 64;

  const __bf16* Qb = Qh + (size_t)bh * 2048 * 64;
  const __bf16* Kb = Kh + (size_t)bh * 2048 * 64;
  const __bf16* Vb = Vt + (size_t)bh * 64 * 2048;

  const int sr0 = tid >> 3, sc0 = tid & 7;
  const int sr1 = (tid + 256) >> 3;

  // Q fragments in registers for the whole block: A[m=l16][k=quad*8+j]
  bf16x8 qa[2];
  for (int ks = 0; ks < 2; ++ks)
    qa[ks] = *(const bf16x8*)
        &Qb[(size_t)(q0 + wid * 16 + l16) * 64 + ks * 32 + quad * 8];

  f32x4 oacc[4];
  for (int i = 0; i < 4; ++i) oacc[i] = zero4();
  float m_i[4], l_i[4];
  for (int r = 0; r < 4; ++r) { m_i[r] = -1e30f; l_i[r] = 0.f; }

  const int kcmax = q0 >> 6;
  for (int kc = 0; kc <= kcmax; ++kc) {
    bf16x8 k0v = *(const bf16x8*)&Kb[(size_t)(kc * 64 + sr0) * 64 + sc0 * 8];
    bf16x8 k1v = *(const bf16x8*)&Kb[(size_t)(kc * 64 + sr1) * 64 + sc0 * 8];
    bf16x8 v0v = *(const bf16x8*)&Vb[(size_t)sr0 * 2048 + kc * 64 + sc0 * 8];
    bf16x8 v1v = *(const bf16x8*)&Vb[(size_t)sr1 * 2048 + kc * 64 + sc0 * 8];
    __syncthreads();   // previous iteration's Ks/Vs reads complete
    *(bf16x8*)&Ks[sr0 * 72 + sc0 * 8] = k0v;
    *(bf16x8*)&Ks[sr1 * 72 + sc0 * 8] = k1v;
    *(bf16x8*)&Vs[sr0 * 72 + sc0 * 8] = v0v;
    *(bf16x8*)&Vs[sr1 * 72 + sc0 * 8] = v1v;
    __syncthreads();

    // S = Q * K^T   (16 q-rows x 64 kpos per wave)
    f32x4 sacc[4];
    for (int i = 0; i < 4; ++i) sacc[i] = zero4();
    for (int ks = 0; ks < 2; ++ks) {
      bf16x8 qf = qa[ks];
      for (int nt = 0; nt < 4; ++nt) {
        bf16x8 kf = *(const bf16x8*)
            &Ks[(nt * 16 + l16) * 72 + ks * 32 + quad * 8];
        sacc[nt] = __builtin_amdgcn_mfma_f32_16x16x32_bf16(
            qf, kf, sacc[nt], 0, 0, 0);
      }
    }

    const bool diag = (kc == kcmax);
    float rmax[4] = {-1e30f, -1e30f, -1e30f, -1e30f};
    for (int nt = 0; nt < 4; ++nt)
      for (int r = 0; r < 4; ++r) {
        float s = sacc[nt][r] * 0.125f;  // Dh^-0.5
        if (diag) {
          int i = wid * 16 + 4 * quad + r;
          int j = nt * 16 + l16;
          if (j > i) s = -1e30f;
        }
        sacc[nt][r] = s;
        rmax[r] = fmaxf(rmax[r], s);
      }
    for (int r = 0; r < 4; ++r)
      for (int off = 1; off < 16; off <<= 1)
        rmax[r] = fmaxf(rmax[r], __shfl_xor(rmax[r], off, 64));

    float alpha[4], rsum[4];
    for (int r = 0; r < 4; ++r) {
      float nm = fmaxf(m_i[r], rmax[r]);
      alpha[r] = expf(m_i[r] - nm);
      m_i[r] = nm;
      rsum[r] = 0.f;
    }
    for (int nt = 0; nt < 4; ++nt)
      for (int r = 0; r < 4; ++r) {
        float p = expf(sacc[nt][r] - m_i[r]);
        rsum[r] += p;
        Ps[(wid * 16 + 4 * quad + r) * 72 + nt * 16 + l16] = (__bf16)p;
      }
    __syncthreads();   // fence Ps write -> vector read
    for (int r = 0; r < 4; ++r) {
      for (int off = 1; off < 16; off <<= 1)
        rsum[r] += __shfl_xor(rsum[r], off, 64);
      l_i[r] = l_i[r] * alpha[r] + rsum[r];
      for (int nt = 0; nt < 4; ++nt) oacc[nt][r] *= alpha[r];
    }

    // O += P * V
    for (int ks = 0; ks < 2; ++ks) {
      bf16x8 pf = *(const bf16x8*)
          &Ps[(wid * 16 + l16) * 72 + ks * 32 + quad * 8];
      for (int nt = 0; nt < 4; ++nt) {
        bf16x8 vf = *(const bf16x8*)
            &Vs[(nt * 16 + l16) * 72 + ks * 32 + quad * 8];
        oacc[nt] = __builtin_amdgcn_mfma_f32_16x16x32_bf16(
            pf, vf, oacc[nt], 0, 0, 0);
      }
    }
  }

  const int b = bh >> 4, h = bh & 15;
  for (int r = 0; r < 4; ++r) {
    float inv = 1.f / l_i[r];
    int gq = q0 + wid * 16 + 4 * quad + r;
    size_t base = (size_t)(b * 2048 + gq) * 1024 + h * 64;
    for (int nt = 0; nt < 4; ++nt)
      AO[base + nt * 16 + l16] = (__bf16)(oacc[nt][r] * inv);
  }
}

// simple d2d copy, 8 bf16 per lane
__global__ __launch_bounds__(256) void copy_bf16x8(
    const __bf16* __restrict__ src, __bf16* __restrict__ dst)
{
  size_t i = ((size_t)blockIdx.x * 256 + threadIdx.x) * 8;
  *(bf16x8*)&dst[i] = *(const bf16x8*)&src[i];
}

// ---------------------------------------------------------------------------
extern "C" void kernel_launch(void* const* d_in, const int* in_sizes, int n_in,
                              void* d_out, int out_size, void* d_ws, size_t ws_size,
                              hipStream_t stream) {
  const float* x  = (const float*)d_in[0];
  const float* Wq = (const float*)d_in[1];
  const float* Wk = (const float*)d_in[2];
  const float* Wv = (const float*)d_in[3];
  const float* Wo = (const float*)d_in[4];
  // d_in[5] = mask (int32 tril, verified on-device in R9) — causal hardcoded.
  float* out = (float*)d_out;                 // FP32 output buffer (16 MiB)
  __bf16* AO = (__bf16*)d_out;                // bf16 staging in first 8 MiB

  const size_t NELT = (size_t)2 * 16 * 2048 * 64;  // 4,194,304 elems (8 MiB)
  __bf16* Qh = (__bf16*)d_ws;       // [bh][t][d]     ws +  0 MiB
  __bf16* Kh = Qh + NELT;           // [bh][t][d]     ws +  8 MiB
  __bf16* Vt = Kh + NELT;           // [bh][d][t]     ws + 16 MiB (24 total)

  // 1. QKV projections (fp32 in) + RoPE + head scatter (bf16 out)
  gemm_nt<<<dim3(8, 32, 3), 256, 0, stream>>>(x, Wq, Wk, Wv, Qh, Kh, Vt,
                                              nullptr, 0, 1, 1);
  // 2. flash attention -> AO (bf16) staged in d_out's first half
  attn_fwd<<<dim3(32, 32), 256, 0, stream>>>(Qh, Kh, Vt, AO);
  // 3. move AO into the now-dead Qh slice
  copy_bf16x8<<<dim3((int)(NELT / (256 * 8))), 256, 0, stream>>>(AO, Qh);
  // 4. output projection: A = AO (bf16), B = Wo (fp32) -> d_out (FP32)
  gemm_nt<<<dim3(8, 32, 1), 256, 0, stream>>>(Qh, Wo, Wo, Wo,
                                              nullptr, nullptr, nullptr, out,
                                              1, 0, 1);
}

// Round 11
// 661.932 us; speedup vs baseline: 1.3458x; 1.3458x over previous
//
#include <hip/hip_runtime.h>
#include <stdint.h>

// MultiHeadAttention w/ RoPE, causal. B=2, T=2048, C=1024, H=16, Dh=64.
// Round 11: memory-traffic overhaul. fp32->bf16 prepass (d_out as scratch),
// GLDS16 staging (m97 pattern), plain-layout + packed epilogue stores (kills
// the 1.5 GB write amplification), XCD-local block decode, in-place AO.

typedef float  f32x4  __attribute__((ext_vector_type(4)));
typedef __bf16 bf16x8 __attribute__((ext_vector_type(8)));
typedef __bf16 bf16x4 __attribute__((ext_vector_type(4)));

#define GLDS16(gp, lp)                                                         \
  __builtin_amdgcn_global_load_lds(                                            \
      (const __attribute__((address_space(1))) void*)(gp),                     \
      (__attribute__((address_space(3))) void*)(lp), 16, 0, 0)

static __device__ __forceinline__ f32x4 zero4() {
  f32x4 z = {0.f, 0.f, 0.f, 0.f};
  return z;
}

static __device__ __forceinline__ bf16x8 cvt8(const float* __restrict__ p) {
  f32x4 u = *(const f32x4*)p;
  f32x4 v = *(const f32x4*)(p + 4);
  bf16x8 o;
#pragma unroll
  for (int j = 0; j < 4; ++j) o[j] = (__bf16)u[j];
#pragma unroll
  for (int j = 0; j < 4; ++j) o[4 + j] = (__bf16)v[j];
  return o;
}

// ---------------------------------------------------------------------------
// Prepass: x (4M f32) -> xb bf16; Wq/Wk/Wv/Wo (1M f32 each) -> Wb bf16[4][1M].
// ---------------------------------------------------------------------------
__global__ __launch_bounds__(256) void prep(
    const float* __restrict__ x,
    const float* __restrict__ Wq, const float* __restrict__ Wk,
    const float* __restrict__ Wv, const float* __restrict__ Wo,
    __bf16* __restrict__ xb, __bf16* __restrict__ Wb)
{
  size_t g = ((size_t)blockIdx.x * 256 + threadIdx.x) * 8;
  if (g < (size_t)4194304) {
    *(bf16x8*)&xb[g] = cvt8(x + g);
  } else {
    size_t j = g - 4194304;
    int w = (int)(j >> 20);
    size_t off = j & 1048575;
    const float* src = (w == 0) ? Wq : (w == 1) ? Wk : (w == 2) ? Wv : Wo;
    *(bf16x8*)&Wb[(size_t)w * 1048576 + off] = cvt8(src + off);
  }
}

// ---------------------------------------------------------------------------
// QKV GEMM (bf16 x bf16): C[m][n] = sum_k xb[m][k]*W[n][k]. 128x128, BK=32,
// GLDS16 staging. Decode: n = lin%8 (XCD-resident W), z fastest, then m.
// z<2: RoPE fused, plain store to Qp/Kp [4096][1024].
// z=2: V^T packed bf16x4 store to Vt [bh][d][t].
// ---------------------------------------------------------------------------
__global__ __launch_bounds__(256) void gemm_qkv(
    const __bf16* __restrict__ xb, const __bf16* __restrict__ Wb,
    __bf16* __restrict__ Qp, __bf16* __restrict__ Kp, __bf16* __restrict__ Vt)
{
  __shared__ __bf16 As[128 * 32];
  __shared__ __bf16 Bs[128 * 32];

  const int tid  = threadIdx.x;
  const int lane = tid & 63;
  const int wid  = tid >> 6;
  const int quad = lane >> 4;
  const int l16  = lane & 15;
  const int wm   = (wid >> 1) * 64;
  const int wn   = (wid & 1) * 64;

  const int lin = blockIdx.x;           // 768 blocks
  const int n0  = (lin & 7) * 128;
  const int r2  = lin >> 3;
  const int z   = r2 % 3;               // z fastest within XCD slot order
  const int m0  = (r2 / 3) * 128;
  const __bf16* Bt = Wb + (size_t)z * 1048576;

  const int r0 = tid >> 2, c0 = tid & 3;
  const int r1 = (tid + 256) >> 2;

  f32x4 acc[4][4];
  for (int i = 0; i < 4; ++i)
    for (int j = 0; j < 4; ++j) acc[i][j] = zero4();

  for (int k0 = 0; k0 < 1024; k0 += 32) {
    __syncthreads();
    GLDS16(xb + (size_t)(m0 + r0) * 1024 + k0 + c0 * 8, &As[(size_t)tid * 8]);
    GLDS16(xb + (size_t)(m0 + r1) * 1024 + k0 + c0 * 8, &As[(size_t)(tid + 256) * 8]);
    GLDS16(Bt + (size_t)(n0 + r0) * 1024 + k0 + c0 * 8, &Bs[(size_t)tid * 8]);
    GLDS16(Bt + (size_t)(n0 + r1) * 1024 + k0 + c0 * 8, &Bs[(size_t)(tid + 256) * 8]);
    __syncthreads();

    bf16x8 af[4], bfr[4];
    for (int i = 0; i < 4; ++i)
      af[i] = *(const bf16x8*)&As[(wm + i * 16 + l16) * 32 + quad * 8];
    for (int i = 0; i < 4; ++i)
      bfr[i] = *(const bf16x8*)&Bs[(wn + i * 16 + l16) * 32 + quad * 8];
    for (int mt = 0; mt < 4; ++mt)
      for (int nt = 0; nt < 4; ++nt)
        acc[mt][nt] = __builtin_amdgcn_mfma_f32_16x16x32_bf16(
            af[mt], bfr[nt], acc[mt][nt], 0, 0, 0);
  }

  // D layout: row = 4*quad + reg, col = l16 per 16x16 subtile.
  const int h = (n0 + wn) >> 6;
  if (z < 2) {
    const float c0f = -13.287712379549449f / 32.0f;  // -log2(10000)/32
    const float f0 = exp2f((float)l16 * c0f);
    const float f1 = exp2f((float)(16 + l16) * c0f);
    for (int mt = 0; mt < 4; ++mt)
      for (int r = 0; r < 4; ++r) {
        int gm = m0 + wm + mt * 16 + 4 * quad + r;
        float t = (float)(gm & 2047);
        for (int nt = 0; nt < 2; ++nt) {
          float ang = t * (nt ? f1 : f0);
          float cv = cosf(ang), sv = sinf(ang);
          float lo = acc[mt][nt][r], hi = acc[mt][nt + 2][r];
          acc[mt][nt][r]     = lo * cv - hi * sv;
          acc[mt][nt + 2][r] = hi * cv + lo * sv;
        }
      }
    __bf16* dst = (z == 0) ? Qp : Kp;
    for (int mt = 0; mt < 4; ++mt)
      for (int r = 0; r < 4; ++r) {
        size_t row = (size_t)(m0 + wm + mt * 16 + 4 * quad + r) * 1024;
        for (int nt = 0; nt < 4; ++nt)
          dst[row + n0 + wn + nt * 16 + l16] = (__bf16)acc[mt][nt][r];
      }
  } else {
    // Vt[(b*16+h)*64 + d][t]; lane's 4 regs = 4 consecutive t at fixed d.
    const int b = m0 >> 11;
    const size_t hb = (size_t)(b * 16 + h) * 64;
    for (int mt = 0; mt < 4; ++mt) {
      int t = ((m0 + wm + mt * 16 + 4 * quad) & 2047);
      for (int nt = 0; nt < 4; ++nt) {
        int d = nt * 16 + l16;
        bf16x4 u = {(__bf16)acc[mt][nt][0], (__bf16)acc[mt][nt][1],
                    (__bf16)acc[mt][nt][2], (__bf16)acc[mt][nt][3]};
        *(bf16x4*)&Vt[(hb + d) * 2048 + t] = u;
      }
    }
  }
}

// ---------------------------------------------------------------------------
// Flash attention (causal). Q/K plain [b*t][1024] (head at col h*64),
// V^T [bh][d][t]. AO written IN-PLACE into QA (each block overwrites exactly
// the rows x cols only it reads). Padded LDS (stride 72).
// ---------------------------------------------------------------------------
__global__ __launch_bounds__(256) void attn_fwd(
    __bf16* QA, const __bf16* __restrict__ Kp,
    const __bf16* __restrict__ Vt)
{
  __shared__ __bf16 Ks[64 * 72];   // [kpos][d]
  __shared__ __bf16 Vs[64 * 72];   // [d][kpos]
  __shared__ __bf16 Ps[64 * 72];   // [q][kpos]

  const int tid  = threadIdx.x;
  const int lane = tid & 63, wid = tid >> 6;
  const int quad = lane >> 4, l16 = lane & 15;
  const int bh = blockIdx.y;
  const int q0 = blockIdx.x * 64;
  const int b = bh >> 4, h = bh & 15;

  const size_t rowb = (size_t)b * 2048;
  const __bf16* Vb = Vt + (size_t)bh * 64 * 2048;

  const int sr0 = tid >> 3, sc0 = tid & 7;
  const int sr1 = (tid + 256) >> 3;

  bf16x8 qa[2];
  for (int ks = 0; ks < 2; ++ks)
    qa[ks] = *(const bf16x8*)
        &QA[(rowb + q0 + wid * 16 + l16) * 1024 + h * 64 + ks * 32 + quad * 8];

  f32x4 oacc[4];
  for (int i = 0; i < 4; ++i) oacc[i] = zero4();
  float m_i[4], l_i[4];
  for (int r = 0; r < 4; ++r) { m_i[r] = -1e30f; l_i[r] = 0.f; }

  const int kcmax = q0 >> 6;
  for (int kc = 0; kc <= kcmax; ++kc) {
    bf16x8 k0v = *(const bf16x8*)&Kp[(rowb + kc * 64 + sr0) * 1024 + h * 64 + sc0 * 8];
    bf16x8 k1v = *(const bf16x8*)&Kp[(rowb + kc * 64 + sr1) * 1024 + h * 64 + sc0 * 8];
    bf16x8 v0v = *(const bf16x8*)&Vb[(size_t)sr0 * 2048 + kc * 64 + sc0 * 8];
    bf16x8 v1v = *(const bf16x8*)&Vb[(size_t)sr1 * 2048 + kc * 64 + sc0 * 8];
    __syncthreads();
    *(bf16x8*)&Ks[sr0 * 72 + sc0 * 8] = k0v;
    *(bf16x8*)&Ks[sr1 * 72 + sc0 * 8] = k1v;
    *(bf16x8*)&Vs[sr0 * 72 + sc0 * 8] = v0v;
    *(bf16x8*)&Vs[sr1 * 72 + sc0 * 8] = v1v;
    __syncthreads();

    f32x4 sacc[4];
    for (int i = 0; i < 4; ++i) sacc[i] = zero4();
    for (int ks = 0; ks < 2; ++ks) {
      bf16x8 qf = qa[ks];
      for (int nt = 0; nt < 4; ++nt) {
        bf16x8 kf = *(const bf16x8*)
            &Ks[(nt * 16 + l16) * 72 + ks * 32 + quad * 8];
        sacc[nt] = __builtin_amdgcn_mfma_f32_16x16x32_bf16(
            qf, kf, sacc[nt], 0, 0, 0);
      }
    }

    const bool diag = (kc == kcmax);
    float rmax[4] = {-1e30f, -1e30f, -1e30f, -1e30f};
    for (int nt = 0; nt < 4; ++nt)
      for (int r = 0; r < 4; ++r) {
        float s = sacc[nt][r] * 0.125f;
        if (diag) {
          int i = wid * 16 + 4 * quad + r;
          int j = nt * 16 + l16;
          if (j > i) s = -1e30f;
        }
        sacc[nt][r] = s;
        rmax[r] = fmaxf(rmax[r], s);
      }
    for (int r = 0; r < 4; ++r)
      for (int off = 1; off < 16; off <<= 1)
        rmax[r] = fmaxf(rmax[r], __shfl_xor(rmax[r], off, 64));

    float alpha[4], rsum[4];
    for (int r = 0; r < 4; ++r) {
      float nm = fmaxf(m_i[r], rmax[r]);
      alpha[r] = expf(m_i[r] - nm);
      m_i[r] = nm;
      rsum[r] = 0.f;
    }
    for (int nt = 0; nt < 4; ++nt)
      for (int r = 0; r < 4; ++r) {
        float p = expf(sacc[nt][r] - m_i[r]);
        rsum[r] += p;
        Ps[(wid * 16 + 4 * quad + r) * 72 + nt * 16 + l16] = (__bf16)p;
      }
    __syncthreads();
    for (int r = 0; r < 4; ++r) {
      for (int off = 1; off < 16; off <<= 1)
        rsum[r] += __shfl_xor(rsum[r], off, 64);
      l_i[r] = l_i[r] * alpha[r] + rsum[r];
      for (int nt = 0; nt < 4; ++nt) oacc[nt][r] *= alpha[r];
    }

    for (int ks = 0; ks < 2; ++ks) {
      bf16x8 pf = *(const bf16x8*)
          &Ps[(wid * 16 + l16) * 72 + ks * 32 + quad * 8];
      for (int nt = 0; nt < 4; ++nt) {
        bf16x8 vf = *(const bf16x8*)
            &Vs[(nt * 16 + l16) * 72 + ks * 32 + quad * 8];
        oacc[nt] = __builtin_amdgcn_mfma_f32_16x16x32_bf16(
            pf, vf, oacc[nt], 0, 0, 0);
      }
    }
  }

  for (int r = 0; r < 4; ++r) {
    float inv = 1.f / l_i[r];
    int gq = q0 + wid * 16 + 4 * quad + r;
    size_t base = (rowb + gq) * 1024 + h * 64;
    for (int nt = 0; nt < 4; ++nt)
      QA[base + nt * 16 + l16] = (__bf16)(oacc[nt][r] * inv);
  }
}

// ---------------------------------------------------------------------------
// Output GEMM: out[m][n] = sum_k AO[m][k]*Wo[n][k], fp32 out, GLDS staging.
// ---------------------------------------------------------------------------
__global__ __launch_bounds__(256) void gemm_out(
    const __bf16* __restrict__ AO, const __bf16* __restrict__ Wob,
    float* __restrict__ Of)
{
  __shared__ __bf16 As[128 * 32];
  __shared__ __bf16 Bs[128 * 32];

  const int tid  = threadIdx.x;
  const int lane = tid & 63;
  const int wid  = tid >> 6;
  const int quad = lane >> 4;
  const int l16  = lane & 15;
  const int wm   = (wid >> 1) * 64;
  const int wn   = (wid & 1) * 64;
  const int lin = blockIdx.x;           // 256 blocks
  const int n0  = (lin & 7) * 128;
  const int m0  = (lin >> 3) * 128;

  const int r0 = tid >> 2, c0 = tid & 3;
  const int r1 = (tid + 256) >> 2;

  f32x4 acc[4][4];
  for (int i = 0; i < 4; ++i)
    for (int j = 0; j < 4; ++j) acc[i][j] = zero4();

  for (int k0 = 0; k0 < 1024; k0 += 32) {
    __syncthreads();
    GLDS16(AO  + (size_t)(m0 + r0) * 1024 + k0 + c0 * 8, &As[(size_t)tid * 8]);
    GLDS16(AO  + (size_t)(m0 + r1) * 1024 + k0 + c0 * 8, &As[(size_t)(tid + 256) * 8]);
    GLDS16(Wob + (size_t)(n0 + r0) * 1024 + k0 + c0 * 8, &Bs[(size_t)tid * 8]);
    GLDS16(Wob + (size_t)(n0 + r1) * 1024 + k0 + c0 * 8, &Bs[(size_t)(tid + 256) * 8]);
    __syncthreads();

    bf16x8 af[4], bfr[4];
    for (int i = 0; i < 4; ++i)
      af[i] = *(const bf16x8*)&As[(wm + i * 16 + l16) * 32 + quad * 8];
    for (int i = 0; i < 4; ++i)
      bfr[i] = *(const bf16x8*)&Bs[(wn + i * 16 + l16) * 32 + quad * 8];
    for (int mt = 0; mt < 4; ++mt)
      for (int nt = 0; nt < 4; ++nt)
        acc[mt][nt] = __builtin_amdgcn_mfma_f32_16x16x32_bf16(
            af[mt], bfr[nt], acc[mt][nt], 0, 0, 0);
  }

  for (int mt = 0; mt < 4; ++mt)
    for (int r = 0; r < 4; ++r) {
      size_t row = (size_t)(m0 + wm + mt * 16 + 4 * quad + r) * 1024;
      for (int nt = 0; nt < 4; ++nt)
        Of[row + n0 + wn + nt * 16 + l16] = acc[mt][nt][r];
    }
}

// copy 8 bf16/lane
__global__ __launch_bounds__(256) void copy_bf16x8(
    const __bf16* __restrict__ src, __bf16* __restrict__ dst)
{
  size_t i = ((size_t)blockIdx.x * 256 + threadIdx.x) * 8;
  *(bf16x8*)&dst[i] = *(const bf16x8*)&src[i];
}

// ---------------------------------------------------------------------------
extern "C" void kernel_launch(void* const* d_in, const int* in_sizes, int n_in,
                              void* d_out, int out_size, void* d_ws, size_t ws_size,
                              hipStream_t stream) {
  const float* x  = (const float*)d_in[0];
  const float* Wq = (const float*)d_in[1];
  const float* Wk = (const float*)d_in[2];
  const float* Wv = (const float*)d_in[3];
  const float* Wo = (const float*)d_in[4];
  float* out = (float*)d_out;

  const size_t NELT = (size_t)4194304;             // 4M elems (8 MiB bf16)
  __bf16* Qp = (__bf16*)d_ws;        // plain Q, becomes AO in-place
  __bf16* Kp = Qp + NELT;            // plain K, later holds Wo bf16
  __bf16* Vt = Kp + NELT;            // V^T [bh][d][t]
  __bf16* xb = (__bf16*)d_out;       // d_out[0:8MB) scratch: x bf16
  __bf16* Wb = xb + NELT;            // d_out[8:16MB): Wq/Wk/Wv/Wo bf16

  // 1. fp32 -> bf16 prepass into d_out scratch
  prep<<<dim3(4096), 256, 0, stream>>>(x, Wq, Wk, Wv, Wo, xb, Wb);
  // 2. QKV projections + RoPE, plain layout (+ packed V^T)
  gemm_qkv<<<dim3(768), 256, 0, stream>>>(xb, Wb, Qp, Kp, Vt);
  // 3. flash attention; AO overwrites Qp in place
  attn_fwd<<<dim3(32, 32), 256, 0, stream>>>(Qp, Kp, Vt);
  // 4. stage Wo bf16 into the now-dead Kp slice (d_out gets overwritten next)
  copy_bf16x8<<<dim3(512), 256, 0, stream>>>(Wb + 3 * NELT / 4, Kp);
  // 5. output projection -> d_out fp32
  gemm_out<<<dim3(256), 256, 0, stream>>>(Qp, Kp, out);
}

// Round 12
// 657.332 us; speedup vs baseline: 1.3552x; 1.0070x over previous
//
#include <hip/hip_runtime.h>
#include <stdint.h>

// MultiHeadAttention w/ RoPE, causal. B=2, T=2048, C=1024, H=16, Dh=64.
// Round 12: kill the 60x HBM write amplification. All epilogues now emit
// full-128B-line b128 stores (one instruction per line) via per-wave LDS
// transpose tiles. gemm_qkv WRITE predicted 1.42 GB -> ~40 MB.

typedef float  f32x4  __attribute__((ext_vector_type(4)));
typedef __bf16 bf16x8 __attribute__((ext_vector_type(8)));

#define GLDS16(gp, lp)                                                         \
  __builtin_amdgcn_global_load_lds(                                            \
      (const __attribute__((address_space(1))) void*)(gp),                     \
      (__attribute__((address_space(3))) void*)(lp), 16, 0, 0)

static __device__ __forceinline__ f32x4 zero4() {
  f32x4 z = {0.f, 0.f, 0.f, 0.f};
  return z;
}

static __device__ __forceinline__ bf16x8 cvt8(const float* __restrict__ p) {
  f32x4 u = *(const f32x4*)p;
  f32x4 v = *(const f32x4*)(p + 4);
  bf16x8 o;
#pragma unroll
  for (int j = 0; j < 4; ++j) o[j] = (__bf16)u[j];
#pragma unroll
  for (int j = 0; j < 4; ++j) o[4 + j] = (__bf16)v[j];
  return o;
}

// ---------------------------------------------------------------------------
// Prepass: x (4M f32) -> xb bf16; Wq/Wk/Wv/Wo (1M f32 each) -> Wb bf16[4][1M].
// ---------------------------------------------------------------------------
__global__ __launch_bounds__(256) void prep(
    const float* __restrict__ x,
    const float* __restrict__ Wq, const float* __restrict__ Wk,
    const float* __restrict__ Wv, const float* __restrict__ Wo,
    __bf16* __restrict__ xb, __bf16* __restrict__ Wb)
{
  size_t g = ((size_t)blockIdx.x * 256 + threadIdx.x) * 8;
  if (g < (size_t)4194304) {
    *(bf16x8*)&xb[g] = cvt8(x + g);
  } else {
    size_t j = g - 4194304;
    int w = (int)(j >> 20);
    size_t off = j & 1048575;
    const float* src = (w == 0) ? Wq : (w == 1) ? Wk : (w == 2) ? Wv : Wo;
    *(bf16x8*)&Wb[(size_t)w * 1048576 + off] = cvt8(src + off);
  }
}

// ---------------------------------------------------------------------------
// QKV GEMM (bf16 x bf16): C[m][n] = sum_k xb[m][k]*W[n][k]. 128x128, BK=32,
// GLDS16 staging. z<2: RoPE fused, plain store Qp/Kp. z=2: V^T [bh][d][t].
// All global stores: full-line b128 via per-wave LDS transpose.
// ---------------------------------------------------------------------------
__global__ __launch_bounds__(256) void gemm_qkv(
    const __bf16* __restrict__ xb, const __bf16* __restrict__ Wb,
    __bf16* __restrict__ Qp, __bf16* __restrict__ Kp, __bf16* __restrict__ Vt)
{
  __shared__ __bf16 As[128 * 32];
  __shared__ __bf16 Bs[128 * 32];
  __shared__ __bf16 Es[4 * 16 * 72];   // per-wave 16x72 transpose tile

  const int tid  = threadIdx.x;
  const int lane = tid & 63;
  const int wid  = tid >> 6;
  const int quad = lane >> 4;
  const int l16  = lane & 15;
  const int wm   = (wid >> 1) * 64;
  const int wn   = (wid & 1) * 64;

  const int lin = blockIdx.x;           // 768 blocks
  const int n0  = (lin & 7) * 128;
  const int r2  = lin >> 3;
  const int z   = r2 % 3;
  const int m0  = (r2 / 3) * 128;
  const __bf16* Bt = Wb + (size_t)z * 1048576;

  const int r0 = tid >> 2, c0 = tid & 3;
  const int r1 = (tid + 256) >> 2;

  f32x4 acc[4][4];
  for (int i = 0; i < 4; ++i)
    for (int j = 0; j < 4; ++j) acc[i][j] = zero4();

  for (int k0 = 0; k0 < 1024; k0 += 32) {
    __syncthreads();
    GLDS16(xb + (size_t)(m0 + r0) * 1024 + k0 + c0 * 8, &As[(size_t)tid * 8]);
    GLDS16(xb + (size_t)(m0 + r1) * 1024 + k0 + c0 * 8, &As[(size_t)(tid + 256) * 8]);
    GLDS16(Bt + (size_t)(n0 + r0) * 1024 + k0 + c0 * 8, &Bs[(size_t)tid * 8]);
    GLDS16(Bt + (size_t)(n0 + r1) * 1024 + k0 + c0 * 8, &Bs[(size_t)(tid + 256) * 8]);
    __syncthreads();

    bf16x8 af[4], bfr[4];
    for (int i = 0; i < 4; ++i)
      af[i] = *(const bf16x8*)&As[(wm + i * 16 + l16) * 32 + quad * 8];
    for (int i = 0; i < 4; ++i)
      bfr[i] = *(const bf16x8*)&Bs[(wn + i * 16 + l16) * 32 + quad * 8];
    for (int mt = 0; mt < 4; ++mt)
      for (int nt = 0; nt < 4; ++nt)
        acc[mt][nt] = __builtin_amdgcn_mfma_f32_16x16x32_bf16(
            af[mt], bfr[nt], acc[mt][nt], 0, 0, 0);
  }

  // D layout: row = 4*quad + reg, col = l16 per 16x16 subtile.
  const int h = (n0 + wn) >> 6;
  __bf16* es = &Es[wid * 1152];        // 16 x 72
  const int rl = lane >> 3, ch = lane & 7;

  if (z < 2) {
    // fused RoPE
    const float c0f = -13.287712379549449f / 32.0f;  // -log2(10000)/32
    const float f0 = exp2f((float)l16 * c0f);
    const float f1 = exp2f((float)(16 + l16) * c0f);
    for (int mt = 0; mt < 4; ++mt)
      for (int r = 0; r < 4; ++r) {
        int gm = m0 + wm + mt * 16 + 4 * quad + r;
        float t = (float)(gm & 2047);
        for (int nt = 0; nt < 2; ++nt) {
          float ang = t * (nt ? f1 : f0);
          float cv = cosf(ang), sv = sinf(ang);
          float lo = acc[mt][nt][r], hi = acc[mt][nt + 2][r];
          acc[mt][nt][r]     = lo * cv - hi * sv;
          acc[mt][nt + 2][r] = hi * cv + lo * sv;
        }
      }
    __bf16* dst = (z == 0) ? Qp : Kp;
    for (int mt = 0; mt < 4; ++mt) {
      __syncthreads();
      for (int nt = 0; nt < 4; ++nt)
        for (int r = 0; r < 4; ++r)
          es[(4 * quad + r) * 72 + nt * 16 + l16] = (__bf16)acc[mt][nt][r];
      __syncthreads();
      size_t g0 = (size_t)(m0 + wm + mt * 16 + rl) * 1024 + n0 + wn + ch * 8;
      *(bf16x8*)&dst[g0]            = *(const bf16x8*)&es[rl * 72 + ch * 8];
      *(bf16x8*)&dst[g0 + 8 * 1024] = *(const bf16x8*)&es[(rl + 8) * 72 + ch * 8];
    }
  } else {
    // V^T: Vt[(b*16+h)*64 + d][t]
    const int b = m0 >> 11;
    const size_t hb = (size_t)(b * 16 + h) * 64;
    const int tt = (m0 + wm) & 2047;
    for (int nt = 0; nt < 4; ++nt) {
      __syncthreads();
      for (int mt = 0; mt < 4; ++mt)
        for (int r = 0; r < 4; ++r)
          es[l16 * 72 + mt * 16 + 4 * quad + r] = (__bf16)acc[mt][nt][r];
      __syncthreads();
      size_t g0 = (hb + nt * 16 + rl) * 2048 + tt + ch * 8;
      *(bf16x8*)&Vt[g0]                     = *(const bf16x8*)&es[rl * 72 + ch * 8];
      *(bf16x8*)&Vt[g0 + (size_t)8 * 2048]  = *(const bf16x8*)&es[(rl + 8) * 72 + ch * 8];
    }
  }
}

// ---------------------------------------------------------------------------
// Flash attention (causal). Q/K plain [b*t][1024] (head at col h*64),
// V^T [bh][d][t]. AO in-place into QA. Full-line output stores via Ps.
// ---------------------------------------------------------------------------
__global__ __launch_bounds__(256) void attn_fwd(
    __bf16* QA, const __bf16* __restrict__ Kp,
    const __bf16* __restrict__ Vt)
{
  __shared__ __bf16 Ks[64 * 72];   // [kpos][d]
  __shared__ __bf16 Vs[64 * 72];   // [d][kpos]
  __shared__ __bf16 Ps[64 * 72];   // [q][kpos] / output transpose buffer

  const int tid  = threadIdx.x;
  const int lane = tid & 63, wid = tid >> 6;
  const int quad = lane >> 4, l16 = lane & 15;
  const int bh = blockIdx.y;
  const int q0 = blockIdx.x * 64;
  const int b = bh >> 4, h = bh & 15;

  const size_t rowb = (size_t)b * 2048;
  const __bf16* Vb = Vt + (size_t)bh * 64 * 2048;

  const int sr0 = tid >> 3, sc0 = tid & 7;
  const int sr1 = (tid + 256) >> 3;

  bf16x8 qa[2];
  for (int ks = 0; ks < 2; ++ks)
    qa[ks] = *(const bf16x8*)
        &QA[(rowb + q0 + wid * 16 + l16) * 1024 + h * 64 + ks * 32 + quad * 8];

  f32x4 oacc[4];
  for (int i = 0; i < 4; ++i) oacc[i] = zero4();
  float m_i[4], l_i[4];
  for (int r = 0; r < 4; ++r) { m_i[r] = -1e30f; l_i[r] = 0.f; }

  const int kcmax = q0 >> 6;
  for (int kc = 0; kc <= kcmax; ++kc) {
    bf16x8 k0v = *(const bf16x8*)&Kp[(rowb + kc * 64 + sr0) * 1024 + h * 64 + sc0 * 8];
    bf16x8 k1v = *(const bf16x8*)&Kp[(rowb + kc * 64 + sr1) * 1024 + h * 64 + sc0 * 8];
    bf16x8 v0v = *(const bf16x8*)&Vb[(size_t)sr0 * 2048 + kc * 64 + sc0 * 8];
    bf16x8 v1v = *(const bf16x8*)&Vb[(size_t)sr1 * 2048 + kc * 64 + sc0 * 8];
    __syncthreads();
    *(bf16x8*)&Ks[sr0 * 72 + sc0 * 8] = k0v;
    *(bf16x8*)&Ks[sr1 * 72 + sc0 * 8] = k1v;
    *(bf16x8*)&Vs[sr0 * 72 + sc0 * 8] = v0v;
    *(bf16x8*)&Vs[sr1 * 72 + sc0 * 8] = v1v;
    __syncthreads();

    f32x4 sacc[4];
    for (int i = 0; i < 4; ++i) sacc[i] = zero4();
    for (int ks = 0; ks < 2; ++ks) {
      bf16x8 qf = qa[ks];
      for (int nt = 0; nt < 4; ++nt) {
        bf16x8 kf = *(const bf16x8*)
            &Ks[(nt * 16 + l16) * 72 + ks * 32 + quad * 8];
        sacc[nt] = __builtin_amdgcn_mfma_f32_16x16x32_bf16(
            qf, kf, sacc[nt], 0, 0, 0);
      }
    }

    const bool diag = (kc == kcmax);
    float rmax[4] = {-1e30f, -1e30f, -1e30f, -1e30f};
    for (int nt = 0; nt < 4; ++nt)
      for (int r = 0; r < 4; ++r) {
        float s = sacc[nt][r] * 0.125f;
        if (diag) {
          int i = wid * 16 + 4 * quad + r;
          int j = nt * 16 + l16;
          if (j > i) s = -1e30f;
        }
        sacc[nt][r] = s;
        rmax[r] = fmaxf(rmax[r], s);
      }
    for (int r = 0; r < 4; ++r)
      for (int off = 1; off < 16; off <<= 1)
        rmax[r] = fmaxf(rmax[r], __shfl_xor(rmax[r], off, 64));

    float alpha[4], rsum[4];
    for (int r = 0; r < 4; ++r) {
      float nm = fmaxf(m_i[r], rmax[r]);
      alpha[r] = expf(m_i[r] - nm);
      m_i[r] = nm;
      rsum[r] = 0.f;
    }
    for (int nt = 0; nt < 4; ++nt)
      for (int r = 0; r < 4; ++r) {
        float p = expf(sacc[nt][r] - m_i[r]);
        rsum[r] += p;
        Ps[(wid * 16 + 4 * quad + r) * 72 + nt * 16 + l16] = (__bf16)p;
      }
    __syncthreads();
    for (int r = 0; r < 4; ++r) {
      for (int off = 1; off < 16; off <<= 1)
        rsum[r] += __shfl_xor(rsum[r], off, 64);
      l_i[r] = l_i[r] * alpha[r] + rsum[r];
      for (int nt = 0; nt < 4; ++nt) oacc[nt][r] *= alpha[r];
    }

    for (int ks = 0; ks < 2; ++ks) {
      bf16x8 pf = *(const bf16x8*)
          &Ps[(wid * 16 + l16) * 72 + ks * 32 + quad * 8];
      for (int nt = 0; nt < 4; ++nt) {
        bf16x8 vf = *(const bf16x8*)
            &Vs[(nt * 16 + l16) * 72 + ks * 32 + quad * 8];
        oacc[nt] = __builtin_amdgcn_mfma_f32_16x16x32_bf16(
            pf, vf, oacc[nt], 0, 0, 0);
      }
    }
  }

  // coalesced output: oacc -> Ps -> full-line b128 stores
  __syncthreads();   // all PV reads of Ps complete
  for (int r = 0; r < 4; ++r) {
    float inv = 1.f / l_i[r];
    for (int nt = 0; nt < 4; ++nt)
      Ps[(wid * 16 + 4 * quad + r) * 72 + nt * 16 + l16] =
          (__bf16)(oacc[nt][r] * inv);
  }
  __syncthreads();
  {
    int row = tid >> 3, ch = tid & 7;        // 32 rows x 8 chunks
    size_t g0 = (rowb + q0 + row) * 1024 + h * 64 + ch * 8;
    *(bf16x8*)&QA[g0]                   = *(const bf16x8*)&Ps[row * 72 + ch * 8];
    *(bf16x8*)&QA[g0 + (size_t)32 * 1024] =
        *(const bf16x8*)&Ps[(row + 32) * 72 + ch * 8];
  }
}

// ---------------------------------------------------------------------------
// Output GEMM: out[m][n] = sum_k AO[m][k]*Wo[n][k], fp32 out, full-line f32x4.
// ---------------------------------------------------------------------------
__global__ __launch_bounds__(256) void gemm_out(
    const __bf16* __restrict__ AO, const __bf16* __restrict__ Wob,
    float* __restrict__ Of)
{
  __shared__ __bf16 As[128 * 32];
  __shared__ __bf16 Bs[128 * 32];
  __shared__ float  EsF[4 * 16 * 68];

  const int tid  = threadIdx.x;
  const int lane = tid & 63;
  const int wid  = tid >> 6;
  const int quad = lane >> 4;
  const int l16  = lane & 15;
  const int wm   = (wid >> 1) * 64;
  const int wn   = (wid & 1) * 64;
  const int lin = blockIdx.x;           // 256 blocks
  const int n0  = (lin & 7) * 128;
  const int m0  = (lin >> 3) * 128;

  const int r0 = tid >> 2, c0 = tid & 3;
  const int r1 = (tid + 256) >> 2;

  f32x4 acc[4][4];
  for (int i = 0; i < 4; ++i)
    for (int j = 0; j < 4; ++j) acc[i][j] = zero4();

  for (int k0 = 0; k0 < 1024; k0 += 32) {
    __syncthreads();
    GLDS16(AO  + (size_t)(m0 + r0) * 1024 + k0 + c0 * 8, &As[(size_t)tid * 8]);
    GLDS16(AO  + (size_t)(m0 + r1) * 1024 + k0 + c0 * 8, &As[(size_t)(tid + 256) * 8]);
    GLDS16(Wob + (size_t)(n0 + r0) * 1024 + k0 + c0 * 8, &Bs[(size_t)tid * 8]);
    GLDS16(Wob + (size_t)(n0 + r1) * 1024 + k0 + c0 * 8, &Bs[(size_t)(tid + 256) * 8]);
    __syncthreads();

    bf16x8 af[4], bfr[4];
    for (int i = 0; i < 4; ++i)
      af[i] = *(const bf16x8*)&As[(wm + i * 16 + l16) * 32 + quad * 8];
    for (int i = 0; i < 4; ++i)
      bfr[i] = *(const bf16x8*)&Bs[(wn + i * 16 + l16) * 32 + quad * 8];
    for (int mt = 0; mt < 4; ++mt)
      for (int nt = 0; nt < 4; ++nt)
        acc[mt][nt] = __builtin_amdgcn_mfma_f32_16x16x32_bf16(
            af[mt], bfr[nt], acc[mt][nt], 0, 0, 0);
  }

  float* es = &EsF[wid * 1088];         // 16 x 68 f32
  const int rl = lane >> 4, ch = lane & 15;
  for (int mt = 0; mt < 4; ++mt) {
    __syncthreads();
    for (int nt = 0; nt < 4; ++nt)
      for (int r = 0; r < 4; ++r)
        es[(4 * quad + r) * 68 + nt * 16 + l16] = acc[mt][nt][r];
    __syncthreads();
    size_t g0 = (size_t)(m0 + wm + mt * 16 + rl) * 1024 + n0 + wn + ch * 4;
    *(f32x4*)&Of[g0]             = *(const f32x4*)&es[rl * 68 + ch * 4];
    *(f32x4*)&Of[g0 + 4 * 1024]  = *(const f32x4*)&es[(rl + 4) * 68 + ch * 4];
    *(f32x4*)&Of[g0 + 8 * 1024]  = *(const f32x4*)&es[(rl + 8) * 68 + ch * 4];
    *(f32x4*)&Of[g0 + 12 * 1024] = *(const f32x4*)&es[(rl + 12) * 68 + ch * 4];
  }
}

// copy 8 bf16/lane
__global__ __launch_bounds__(256) void copy_bf16x8(
    const __bf16* __restrict__ src, __bf16* __restrict__ dst)
{
  size_t i = ((size_t)blockIdx.x * 256 + threadIdx.x) * 8;
  *(bf16x8*)&dst[i] = *(const bf16x8*)&src[i];
}

// ---------------------------------------------------------------------------
extern "C" void kernel_launch(void* const* d_in, const int* in_sizes, int n_in,
                              void* d_out, int out_size, void* d_ws, size_t ws_size,
                              hipStream_t stream) {
  const float* x  = (const float*)d_in[0];
  const float* Wq = (const float*)d_in[1];
  const float* Wk = (const float*)d_in[2];
  const float* Wv = (const float*)d_in[3];
  const float* Wo = (const float*)d_in[4];
  float* out = (float*)d_out;

  const size_t NELT = (size_t)4194304;             // 4M elems (8 MiB bf16)
  __bf16* Qp = (__bf16*)d_ws;        // plain Q, becomes AO in-place
  __bf16* Kp = Qp + NELT;            // plain K, later holds Wo bf16
  __bf16* Vt = Kp + NELT;            // V^T [bh][d][t]
  __bf16* xb = (__bf16*)d_out;       // d_out[0:8MB) scratch: x bf16
  __bf16* Wb = xb + NELT;            // d_out[8:16MB): W* bf16

  prep<<<dim3(4096), 256, 0, stream>>>(x, Wq, Wk, Wv, Wo, xb, Wb);
  gemm_qkv<<<dim3(768), 256, 0, stream>>>(xb, Wb, Qp, Kp, Vt);
  attn_fwd<<<dim3(32, 32), 256, 0, stream>>>(Qp, Kp, Vt);
  copy_bf16x8<<<dim3(512), 256, 0, stream>>>(Wb + 3 * NELT / 4, Kp);
  gemm_out<<<dim3(256), 256, 0, stream>>>(Qp, Kp, out);
}